// Round 1
// baseline (168.228 us; speedup 1.0000x reference)
//
#include <hip/hip_runtime.h>
#include <hip/hip_bf16.h>
#include <stdint.h>
#include <stddef.h>

#define SEQ  8192
#define DIN  1024
#define DOUT 1024

typedef __hip_bfloat16 bf16;
typedef short bf16x8 __attribute__((ext_vector_type(8)));   // 8 bf16 = 4 VGPRs
typedef float f32x4  __attribute__((ext_vector_type(4)));

// async global->LDS, 16B per lane; dest = wave-uniform base + lane*16
#define GLOAD_LDS16(gptr, lptr)                                                     \
  __builtin_amdgcn_global_load_lds(                                                 \
      (const __attribute__((address_space(1))) void*)(gptr),                        \
      (__attribute__((address_space(3))) void*)(lptr), 16, 0, 0)

__device__ inline void store_out(float* p, float v) { *p = v; }
__device__ inline void store_out(bf16* p, float v) { *p = __float2bfloat16(v); }
__device__ inline short bfbits(float f) { bf16 b = __float2bfloat16(f); return *(short*)&b; }
__device__ inline float bf2f(short u) {
  unsigned v = ((unsigned)(unsigned short)u) << 16;
  return __uint_as_float(v);
}

// ---------------------------------------------------------------------------
// 128x128 tile, BK=64, XOR-swizzled LDS, DOUBLE-BUFFERED (prefetch 1 tile,
// vmcnt(8) one-iter-late wait, raw s_barrier -> no full drain per iter).
// As/Bs each hold 2 buffers of 128*64 bf16 (16 KB) -> 64 KB total LDS.
template <typename OutT>
__device__ __forceinline__ void gemm128_body(
    const bf16* __restrict__ A, const bf16* __restrict__ B, OutT* __restrict__ C,
    int bx, int by, int K, int lda, int ldb, int ldc, bf16* As, bf16* Bs)
{
  const int lane = threadIdx.x & 63;
  const int wave = threadIdx.x >> 6;
  const int m0 = by * 128, n0 = bx * 128;

  const int sR = lane >> 3;
  const int sC = (lane & 7) ^ sR;       // XOR swizzle -> conflict-free b128 reads
  const bf16* gA = A + (size_t)(m0 + sR) * lda + sC * 8;
  const bf16* gB = B + (size_t)(n0 + sR) * ldb + sC * 8;

  f32x4 acc[4][4];
#pragma unroll
  for (int i = 0; i < 4; ++i)
#pragma unroll
    for (int j = 0; j < 4; ++j)
      acc[i][j] = (f32x4){0.f, 0.f, 0.f, 0.f};

  const int wr = wave >> 1, wc = wave & 1;
  const int mW = wr * 64, nW = wc * 64;
  const int fragRow = lane & 15;
  const int quad = lane >> 4;

  auto stage = [&](int kt, int buf) {
    bf16* dA = As + buf * (128 * 64);
    bf16* dB = Bs + buf * (128 * 64);
#pragma unroll
    for (int t = 0; t < 4; ++t) {
      const int R = (t * 4 + wave) * 8;
      GLOAD_LDS16(gA + (size_t)R * lda + kt, &dA[R * 64]);
      GLOAD_LDS16(gB + (size_t)R * ldb + kt, &dB[R * 64]);
    }
  };

  const int nT = K >> 6;
  stage(0, 0);
  for (int kt = 0; kt < nT; ++kt) {
    const int buf = kt & 1;
    if (kt + 1 < nT) {
      stage((kt + 1) << 6, buf ^ 1);
      asm volatile("s_waitcnt vmcnt(8)" ::: "memory");   // wait tile kt only
    } else {
      asm volatile("s_waitcnt vmcnt(0)" ::: "memory");
    }
    asm volatile("s_barrier" ::: "memory");

    const bf16* Ab = As + buf * (128 * 64);
    const bf16* Bb = Bs + buf * (128 * 64);
    bf16x8 afr[2][4], bfr[2][4];
#pragma unroll
    for (int s = 0; s < 2; ++s) {
      const int cw = s * 4 + quad;
#pragma unroll
      for (int i = 0; i < 4; ++i) {
        const int ra = mW + i * 16 + fragRow;
        afr[s][i] = *(const bf16x8*)&Ab[ra * 64 + ((cw ^ (ra & 7)) << 3)];
        const int rb = nW + i * 16 + fragRow;
        bfr[s][i] = *(const bf16x8*)&Bb[rb * 64 + ((cw ^ (rb & 7)) << 3)];
      }
    }
    asm volatile("s_waitcnt lgkmcnt(0)" ::: "memory");   // frags in regs
    asm volatile("s_barrier" ::: "memory");              // buf safe to refill

#pragma unroll
    for (int s = 0; s < 2; ++s)
#pragma unroll
      for (int i = 0; i < 4; ++i)
#pragma unroll
        for (int j = 0; j < 4; ++j)
          acc[i][j] = __builtin_amdgcn_mfma_f32_16x16x32_bf16(afr[s][i], bfr[s][j], acc[i][j], 0, 0, 0);
  }

  const int cCol  = lane & 15;
  const int cRow4 = quad * 4;
#pragma unroll
  for (int i = 0; i < 4; ++i)
#pragma unroll
    for (int j = 0; j < 4; ++j) {
      const int row = m0 + mW + i * 16 + cRow4;
      const int col = n0 + nW + j * 16 + cCol;
#pragma unroll
      for (int r = 0; r < 4; ++r)
        store_out(&C[(size_t)(row + r) * ldc + col], acc[i][j][r]);
    }
}

// 64x64 tile, BK=64, same swizzle, double-buffered. As/Bs each 2*64*64 bf16.
template <typename OutT>
__device__ __forceinline__ void gemm64_body(
    const bf16* __restrict__ A, const bf16* __restrict__ B, OutT* __restrict__ C,
    int bx, int by, int K, int lda, int ldb, int ldc, bf16* As, bf16* Bs)
{
  const int lane = threadIdx.x & 63;
  const int wave = threadIdx.x >> 6;
  const int m0 = by * 64, n0 = bx * 64;

  const int sR = lane >> 3;
  const int sC = (lane & 7) ^ sR;
  const bf16* gA = A + (size_t)(m0 + sR) * lda + sC * 8;
  const bf16* gB = B + (size_t)(n0 + sR) * ldb + sC * 8;

  f32x4 acc[2][2];
#pragma unroll
  for (int i = 0; i < 2; ++i)
#pragma unroll
    for (int j = 0; j < 2; ++j)
      acc[i][j] = (f32x4){0.f, 0.f, 0.f, 0.f};

  const int wr = wave >> 1, wc = wave & 1;
  const int mW = wr * 32, nW = wc * 32;
  const int fragRow = lane & 15;
  const int quad = lane >> 4;

  auto stage = [&](int kt, int buf) {
    bf16* dA = As + buf * (64 * 64);
    bf16* dB = Bs + buf * (64 * 64);
#pragma unroll
    for (int t = 0; t < 2; ++t) {
      const int R = (t * 4 + wave) * 8;
      GLOAD_LDS16(gA + (size_t)R * lda + kt, &dA[R * 64]);
      GLOAD_LDS16(gB + (size_t)R * ldb + kt, &dB[R * 64]);
    }
  };

  const int nT = K >> 6;
  stage(0, 0);
  for (int kt = 0; kt < nT; ++kt) {
    const int buf = kt & 1;
    if (kt + 1 < nT) {
      stage((kt + 1) << 6, buf ^ 1);
      asm volatile("s_waitcnt vmcnt(4)" ::: "memory");
    } else {
      asm volatile("s_waitcnt vmcnt(0)" ::: "memory");
    }
    asm volatile("s_barrier" ::: "memory");

    const bf16* Ab = As + buf * (64 * 64);
    const bf16* Bb = Bs + buf * (64 * 64);
    bf16x8 afr[2][2], bfr[2][2];
#pragma unroll
    for (int s = 0; s < 2; ++s) {
      const int cw = s * 4 + quad;
#pragma unroll
      for (int i = 0; i < 2; ++i) {
        const int ra = mW + i * 16 + fragRow;
        afr[s][i] = *(const bf16x8*)&Ab[ra * 64 + ((cw ^ (ra & 7)) << 3)];
        const int rb = nW + i * 16 + fragRow;
        bfr[s][i] = *(const bf16x8*)&Bb[rb * 64 + ((cw ^ (rb & 7)) << 3)];
      }
    }
    asm volatile("s_waitcnt lgkmcnt(0)" ::: "memory");
    asm volatile("s_barrier" ::: "memory");

#pragma unroll
    for (int s = 0; s < 2; ++s)
#pragma unroll
      for (int i = 0; i < 2; ++i)
#pragma unroll
        for (int j = 0; j < 2; ++j)
          acc[i][j] = __builtin_amdgcn_mfma_f32_16x16x32_bf16(afr[s][i], bfr[s][j], acc[i][j], 0, 0, 0);
  }

  const int cCol  = lane & 15;
  const int cRow4 = quad * 4;
#pragma unroll
  for (int i = 0; i < 2; ++i)
#pragma unroll
    for (int j = 0; j < 2; ++j) {
      const int row = m0 + mW + i * 16 + cRow4;
      const int col = n0 + nW + j * 16 + cCol;
#pragma unroll
      for (int r = 0; r < 4; ++r)
        store_out(&C[(size_t)(row + r) * ldc + col], acc[i][j][r]);
    }
}

// ---------------------------------------------------------------------------
// P1 = WQ WK^T from RAW f32 inputs (no pre-cast needed). 64x64 tile, K=1024,
// ld=1024. Reg-staged cast -> PADDED LDS (stride 72: bank-conflict-floor for
// both ds_write_b128 and ds_read_b128, no XOR needed since we control both
// sides). Single-buffered: these blocks ride inside the BW-bound prep kernel,
// so their MFMA/VALU hides under prep's HBM stalls.
__device__ __forceinline__ void p1_body(
    const float* __restrict__ A, const float* __restrict__ B, bf16* __restrict__ C,
    int bx, int by, bf16* As, bf16* Bs)
{
  const int tid  = threadIdx.x;
  const int lane = tid & 63;
  const int wave = tid >> 6;
  const int m0 = by * 64, n0 = bx * 64;

  const int sRow = tid >> 2;          // 0..63 : staged row
  const int sJ   = (tid & 3) << 1;    // slots sJ, sJ+1 (8 bf16 each)

  f32x4 acc[2][2];
#pragma unroll
  for (int i = 0; i < 2; ++i)
#pragma unroll
    for (int j = 0; j < 2; ++j)
      acc[i][j] = (f32x4){0.f, 0.f, 0.f, 0.f};

  const int wr = wave >> 1, wc = wave & 1;
  const int mW = wr * 32, nW = wc * 32;
  const int fragRow = lane & 15;
  const int quad = lane >> 4;

  const float* gA = A + (size_t)(m0 + sRow) * 1024;
  const float* gB = B + (size_t)(n0 + sRow) * 1024;

  for (int kt = 0; kt < 16; ++kt) {
    const int k0 = kt << 6;
    float4 ra[2][2], rb[2][2];
#pragma unroll
    for (int u = 0; u < 2; ++u) {
      const int c = k0 + ((sJ + u) << 3);
      ra[u][0] = *(const float4*)&gA[c];
      ra[u][1] = *(const float4*)&gA[c + 4];
      rb[u][0] = *(const float4*)&gB[c];
      rb[u][1] = *(const float4*)&gB[c + 4];
    }
    __syncthreads();                    // prev-iter frag reads complete
#pragma unroll
    for (int u = 0; u < 2; ++u) {
      bf16x8 pa, pb;
      pa[0] = bfbits(ra[u][0].x); pa[1] = bfbits(ra[u][0].y);
      pa[2] = bfbits(ra[u][0].z); pa[3] = bfbits(ra[u][0].w);
      pa[4] = bfbits(ra[u][1].x); pa[5] = bfbits(ra[u][1].y);
      pa[6] = bfbits(ra[u][1].z); pa[7] = bfbits(ra[u][1].w);
      pb[0] = bfbits(rb[u][0].x); pb[1] = bfbits(rb[u][0].y);
      pb[2] = bfbits(rb[u][0].z); pb[3] = bfbits(rb[u][0].w);
      pb[4] = bfbits(rb[u][1].x); pb[5] = bfbits(rb[u][1].y);
      pb[6] = bfbits(rb[u][1].z); pb[7] = bfbits(rb[u][1].w);
      *(bf16x8*)&As[sRow * 72 + (sJ + u) * 8] = pa;
      *(bf16x8*)&Bs[sRow * 72 + (sJ + u) * 8] = pb;
    }
    __syncthreads();

    bf16x8 afr[2][2], bfr[2][2];
#pragma unroll
    for (int s = 0; s < 2; ++s) {
      const int cw = s * 4 + quad;
#pragma unroll
      for (int i = 0; i < 2; ++i) {
        const int rr = mW + i * 16 + fragRow;
        afr[s][i] = *(const bf16x8*)&As[rr * 72 + cw * 8];
        const int cc = nW + i * 16 + fragRow;
        bfr[s][i] = *(const bf16x8*)&Bs[cc * 72 + cw * 8];
      }
    }
#pragma unroll
    for (int s = 0; s < 2; ++s)
#pragma unroll
      for (int i = 0; i < 2; ++i)
#pragma unroll
        for (int j = 0; j < 2; ++j)
          acc[i][j] = __builtin_amdgcn_mfma_f32_16x16x32_bf16(afr[s][i], bfr[s][j], acc[i][j], 0, 0, 0);
  }

  const int cCol  = lane & 15;
  const int cRow4 = quad * 4;
#pragma unroll
  for (int i = 0; i < 2; ++i)
#pragma unroll
    for (int j = 0; j < 2; ++j) {
      const int row = m0 + mW + i * 16 + cRow4;
      const int col = n0 + nW + j * 16 + cCol;
#pragma unroll
      for (int r = 0; r < 4; ++r)
        store_out(&C[(size_t)(row + r) * 1024 + col], acc[i][j][r]);
    }
}

// ---------------------------------------------------------------------------
// G split-K partials only: 512 blocks = exactly 2 blocks/CU * 256 CU, ONE
// clean co-residency round (the old 768-block merged kernel ran a ragged
// half-empty second round). z = b&7 -> one K-chunk per XCD, 2 MB xTb slice
// L2-resident, 16x reuse.
__global__ __launch_bounds__(256) void g_G(
    const bf16* __restrict__ xT, bf16* __restrict__ part)
{
  __shared__ bf16 sm[4 * 128 * 64];  // 64 KB
  const int b = blockIdx.x;
  const int z = b & 7;      // XCD round-robin -> chunk z stays on one XCD
  const int r = b >> 3;     // 64 output tiles
  const bf16* Az = xT + (size_t)z * 1024;
  gemm128_body<bf16>(Az, Az, part + ((size_t)z << 20),
                     r & 7, r >> 3, 1024, 8192, 8192, 1024,
                     sm, sm + 2 * 128 * 64);
}

// final GEMM: XCD-swizzled so each XCD owns 8 consecutive by (A rows 2 MB,
// L2-resident, 8x reuse). grid 512 = 8 xcd * 8 by * 8 bx.
__global__ __launch_bounds__(256) void gemm128_f32(
    const bf16* __restrict__ A, const bf16* __restrict__ B, float* __restrict__ C,
    int K, int lda, int ldb, int ldc)
{
  __shared__ bf16 sm[4 * 128 * 64];
  const int id = blockIdx.x;
  const int by = ((id & 7) << 3) | ((id >> 3) & 7);
  const int bx = id >> 6;
  gemm128_body<float>(A, B, C, bx, by, K, lda, ldb, ldc, sm, sm + 2 * 128 * 64);
}

__global__ __launch_bounds__(256) void gemm64_bf(
    const bf16* __restrict__ A, const bf16* __restrict__ B, bf16* __restrict__ C,
    int K, int lda, int ldb, int ldc)
{
  __shared__ bf16 sm[4 * 64 * 64];
  gemm64_body<bf16>(A, B, C, blockIdx.x, blockIdx.y, K, lda, ldb, ldc,
                    sm, sm + 2 * 64 * 64);
}

// ---------------------------------------------------------------------------
// prep_all, one dispatch (1408 blocks):
//   blocks 0..255     : P1 = WQ WK^T directly from f32 (MFMA work hides under
//                       the BW-bound transpose blocks; placed FIRST so they
//                       start immediately)
//   blocks 256..1279  : transpose x -> xTb AND fused straight-cast x -> xb
//                       (x is read ONCE instead of twice; WQ/WK casts deleted)
//   blocks 1280..1407 : transpose WV -> WVTb
__global__ __launch_bounds__(256) void prep_all(
    const float* __restrict__ x, const float* __restrict__ WQ,
    const float* __restrict__ WK, const float* __restrict__ WV,
    bf16* __restrict__ xb, bf16* __restrict__ xTb,
    bf16* __restrict__ WVTb, bf16* __restrict__ P1)
{
  __shared__ __align__(16) bf16 sm[2 * 64 * 72];   // 18.4 KB (union of uses)
  int b = blockIdx.x;

  if (b < 256) {
    p1_body(WQ, WK, P1, b & 15, b >> 4, sm, sm + 64 * 72);
    return;
  }
  b -= 256;

  bf16 (*t)[68] = (bf16(*)[68])sm;   // row stride 68: b64-aligned, low conflict
  const float* src; bf16* dst; int ldOut, tr, tc; bool isX;
  if (b < 1024) { src = x;  dst = xTb;  ldOut = SEQ; tr = b >> 4; tc = b & 15; isX = true; }
  else { b -= 1024; src = WV; dst = WVTb; ldOut = DIN; tr = b >> 4; tc = b & 15; isX = false; }
  const int r0 = tr * 128, c0 = tc * 64;

  // phase 1: 128 rows x 64 cols fp32, float4 reads -> short4 LDS writes
  //          (+ fused straight bf16 cast store for x)
#pragma unroll
  for (int p = 0; p < 8; ++p) {
    const int q = threadIdx.x + p * 256;   // float4 id, 0..2047
    const int r = q >> 4, c4 = (q & 15) * 4;
    const float4 f = *(const float4*)&src[(size_t)(r0 + r) * DIN + c0 + c4];
    short4 s4;
    s4.x = bfbits(f.x); s4.y = bfbits(f.y); s4.z = bfbits(f.z); s4.w = bfbits(f.w);
    *(short4*)&t[r][c4] = s4;
    if (isX) *(short4*)&xb[(size_t)(r0 + r) * DIN + c0 + c4] = s4;
  }
  __syncthreads();

  // phase 2: 64 outT-rows x 256 B, bf16x8 16B stores (16 lanes per row)
#pragma unroll
  for (int p = 0; p < 4; ++p) {
    const int h = threadIdx.x + p * 256;   // 0..1023
    const int c = h >> 4, seg = h & 15;
    bf16x8 o;
#pragma unroll
    for (int i = 0; i < 8; ++i)
      o[i] = *(const short*)&t[seg * 8 + i][c];
    *(bf16x8*)&dst[(size_t)(c0 + c) * ldOut + r0 + seg * 8] = o;
  }
}

// sum 8 bf16 partials (stride 1M elems) -> bf16; 8 elems (16B) per thread
__global__ void reduce8(const bf16* __restrict__ part, bf16* __restrict__ out, int S)
{
  const int i = blockIdx.x * blockDim.x + threadIdx.x;
  const size_t base = (size_t)i * 8;
  float s[8] = {0.f, 0.f, 0.f, 0.f, 0.f, 0.f, 0.f, 0.f};
  for (int z = 0; z < S; ++z) {
    bf16x8 v = *(const bf16x8*)&part[((size_t)z << 20) + base];
#pragma unroll
    for (int r = 0; r < 8; ++r) s[r] += bf2f(v[r]);
  }
  bf16x8 o;
#pragma unroll
  for (int r = 0; r < 8; ++r) o[r] = bfbits(s[r]);
  *(bf16x8*)&out[base] = o;
}

// ---------------------------------------------------------------------------
extern "C" void kernel_launch(void* const* d_in, const int* in_sizes, int n_in,
                              void* d_out, int out_size, void* d_ws, size_t ws_size,
                              hipStream_t stream)
{
  const float* x  = (const float*)d_in[0];
  const float* WQ = (const float*)d_in[1];
  const float* WK = (const float*)d_in[2];
  const float* WV = (const float*)d_in[3];
  float* out = (float*)d_out;

  char* ws = (char*)d_ws;
  size_t off = 0;
  auto alloc = [&](size_t bytes) -> void* {
    void* p = ws + off;
    off += (bytes + 255) & ~(size_t)255;
    return p;
  };

  const size_t xBytes = (size_t)SEQ * DIN * sizeof(bf16);
  const size_t wBytes = (size_t)DIN * DOUT * sizeof(bf16);
  const int S = 8;

  bf16* xb   = (bf16*)alloc(xBytes);   // x, bf16
  bf16* xTb  = (bf16*)alloc(xBytes);   // x^T, bf16
  bf16* WVTb = (bf16*)alloc(wBytes);   // WV^T
  bf16* Gb   = (bf16*)alloc(wBytes);   // x^T x (symmetric)
  bf16* P1b  = (bf16*)alloc(wBytes);   // WQ WK^T
  bf16* Utb  = (bf16*)alloc(wBytes);   // (G WV)^T = WV^T G
  bf16* WpTb = (bf16*)alloc(wBytes);   // W'^T = Ut P1^T
  bf16* part = (bf16*)alloc((size_t)S * wBytes);  // split-K partials

  // 1. casts + transposes + P1 (from raw f32), one dispatch
  prep_all<<<dim3(1408), 256, 0, stream>>>(x, WQ, WK, WV, xb, xTb, WVTb, P1b);

  // 2. G split-K partials (XCD-localized), clean single round of 512 blocks
  g_G<<<dim3(512), 256, 0, stream>>>(xTb, part);

  // 3. G = sum partials
  reduce8<<<dim3(512), 256, 0, stream>>>(part, Gb, S);

  // 4. Ut = WV^T G  (= (G WV)^T, G symmetric)
  gemm64_bf<<<dim3(16, 16), 256, 0, stream>>>(WVTb, Gb, Utb, 1024, 1024, 1024, 1024);
  // 5. W'^T = Ut P1^T
  gemm64_bf<<<dim3(16, 16), 256, 0, stream>>>(Utb, P1b, WpTb, 1024, 1024, 1024, 1024);

  // 6. out = x W'  (XCD-swizzled)
  gemm128_f32<<<dim3(512), 256, 0, stream>>>(xb, WpTb, out, 1024, 1024, 1024, DOUT);
}

// Round 2
// 160.988 us; speedup vs baseline: 1.0450x; 1.0450x over previous
//
#include <hip/hip_runtime.h>
#include <hip/hip_bf16.h>
#include <stdint.h>
#include <stddef.h>

#define SEQ  8192
#define DIN  1024
#define DOUT 1024

typedef __hip_bfloat16 bf16;
typedef short bf16x8 __attribute__((ext_vector_type(8)));   // 8 bf16 = 4 VGPRs
typedef float f32x4  __attribute__((ext_vector_type(4)));

// async global->LDS, 16B per lane; dest = wave-uniform base + lane*16
#define GLOAD_LDS16(gptr, lptr)                                                     \
  __builtin_amdgcn_global_load_lds(                                                 \
      (const __attribute__((address_space(1))) void*)(gptr),                        \
      (__attribute__((address_space(3))) void*)(lptr), 16, 0, 0)

__device__ inline void store_out(float* p, float v) { *p = v; }
__device__ inline void store_out(bf16* p, float v) { *p = __float2bfloat16(v); }
__device__ inline short bfbits(float f) { bf16 b = __float2bfloat16(f); return *(short*)&b; }
__device__ inline float bf2f(short u) {
  unsigned v = ((unsigned)(unsigned short)u) << 16;
  return __uint_as_float(v);
}

// upper-triangle tile id t in [0,36) -> (ti,tj), ti<=tj, 8x8 tile grid
__device__ inline void tri_map(int t, int& ti, int& tj) {
  int a = 0, rem = t;
  while (rem >= 8 - a) { rem -= 8 - a; ++a; }
  ti = a; tj = a + rem;
}

// ---------------------------------------------------------------------------
// 128x128 tile, BK=64, XOR-swizzled LDS, DOUBLE-BUFFERED (prefetch 1 tile,
// vmcnt(8) one-iter-late wait, raw s_barrier -> no full drain per iter).
// As/Bs each hold 2 buffers of 128*64 bf16 (16 KB) -> 64 KB total LDS.
template <typename OutT>
__device__ __forceinline__ void gemm128_body(
    const bf16* __restrict__ A, const bf16* __restrict__ B, OutT* __restrict__ C,
    int bx, int by, int K, int lda, int ldb, int ldc, bf16* As, bf16* Bs)
{
  const int lane = threadIdx.x & 63;
  const int wave = threadIdx.x >> 6;
  const int m0 = by * 128, n0 = bx * 128;

  const int sR = lane >> 3;
  const int sC = (lane & 7) ^ sR;       // XOR swizzle -> conflict-free b128 reads
  const bf16* gA = A + (size_t)(m0 + sR) * lda + sC * 8;
  const bf16* gB = B + (size_t)(n0 + sR) * ldb + sC * 8;

  f32x4 acc[4][4];
#pragma unroll
  for (int i = 0; i < 4; ++i)
#pragma unroll
    for (int j = 0; j < 4; ++j)
      acc[i][j] = (f32x4){0.f, 0.f, 0.f, 0.f};

  const int wr = wave >> 1, wc = wave & 1;
  const int mW = wr * 64, nW = wc * 64;
  const int fragRow = lane & 15;
  const int quad = lane >> 4;

  auto stage = [&](int kt, int buf) {
    bf16* dA = As + buf * (128 * 64);
    bf16* dB = Bs + buf * (128 * 64);
#pragma unroll
    for (int t = 0; t < 4; ++t) {
      const int R = (t * 4 + wave) * 8;
      GLOAD_LDS16(gA + (size_t)R * lda + kt, &dA[R * 64]);
      GLOAD_LDS16(gB + (size_t)R * ldb + kt, &dB[R * 64]);
    }
  };

  const int nT = K >> 6;
  stage(0, 0);
  for (int kt = 0; kt < nT; ++kt) {
    const int buf = kt & 1;
    if (kt + 1 < nT) {
      stage((kt + 1) << 6, buf ^ 1);
      asm volatile("s_waitcnt vmcnt(8)" ::: "memory");   // wait tile kt only
    } else {
      asm volatile("s_waitcnt vmcnt(0)" ::: "memory");
    }
    asm volatile("s_barrier" ::: "memory");

    const bf16* Ab = As + buf * (128 * 64);
    const bf16* Bb = Bs + buf * (128 * 64);
    bf16x8 afr[2][4], bfr[2][4];
#pragma unroll
    for (int s = 0; s < 2; ++s) {
      const int cw = s * 4 + quad;
#pragma unroll
      for (int i = 0; i < 4; ++i) {
        const int ra = mW + i * 16 + fragRow;
        afr[s][i] = *(const bf16x8*)&Ab[ra * 64 + ((cw ^ (ra & 7)) << 3)];
        const int rb = nW + i * 16 + fragRow;
        bfr[s][i] = *(const bf16x8*)&Bb[rb * 64 + ((cw ^ (rb & 7)) << 3)];
      }
    }
    asm volatile("s_waitcnt lgkmcnt(0)" ::: "memory");   // frags in regs
    asm volatile("s_barrier" ::: "memory");              // buf safe to refill

#pragma unroll
    for (int s = 0; s < 2; ++s)
#pragma unroll
      for (int i = 0; i < 4; ++i)
#pragma unroll
        for (int j = 0; j < 4; ++j)
          acc[i][j] = __builtin_amdgcn_mfma_f32_16x16x32_bf16(afr[s][i], bfr[s][j], acc[i][j], 0, 0, 0);
  }

  const int cCol  = lane & 15;
  const int cRow4 = quad * 4;
#pragma unroll
  for (int i = 0; i < 4; ++i)
#pragma unroll
    for (int j = 0; j < 4; ++j) {
      const int row = m0 + mW + i * 16 + cRow4;
      const int col = n0 + nW + j * 16 + cCol;
#pragma unroll
      for (int r = 0; r < 4; ++r)
        store_out(&C[(size_t)(row + r) * ldc + col], acc[i][j][r]);
    }
}

// 64x64 tile, BK=64, same swizzle, double-buffered. As/Bs each 2*64*64 bf16.
template <typename OutT>
__device__ __forceinline__ void gemm64_body(
    const bf16* __restrict__ A, const bf16* __restrict__ B, OutT* __restrict__ C,
    int bx, int by, int K, int lda, int ldb, int ldc, bf16* As, bf16* Bs)
{
  const int lane = threadIdx.x & 63;
  const int wave = threadIdx.x >> 6;
  const int m0 = by * 64, n0 = bx * 64;

  const int sR = lane >> 3;
  const int sC = (lane & 7) ^ sR;
  const bf16* gA = A + (size_t)(m0 + sR) * lda + sC * 8;
  const bf16* gB = B + (size_t)(n0 + sR) * ldb + sC * 8;

  f32x4 acc[2][2];
#pragma unroll
  for (int i = 0; i < 2; ++i)
#pragma unroll
    for (int j = 0; j < 2; ++j)
      acc[i][j] = (f32x4){0.f, 0.f, 0.f, 0.f};

  const int wr = wave >> 1, wc = wave & 1;
  const int mW = wr * 32, nW = wc * 32;
  const int fragRow = lane & 15;
  const int quad = lane >> 4;

  auto stage = [&](int kt, int buf) {
    bf16* dA = As + buf * (64 * 64);
    bf16* dB = Bs + buf * (64 * 64);
#pragma unroll
    for (int t = 0; t < 2; ++t) {
      const int R = (t * 4 + wave) * 8;
      GLOAD_LDS16(gA + (size_t)R * lda + kt, &dA[R * 64]);
      GLOAD_LDS16(gB + (size_t)R * ldb + kt, &dB[R * 64]);
    }
  };

  const int nT = K >> 6;
  stage(0, 0);
  for (int kt = 0; kt < nT; ++kt) {
    const int buf = kt & 1;
    if (kt + 1 < nT) {
      stage((kt + 1) << 6, buf ^ 1);
      asm volatile("s_waitcnt vmcnt(4)" ::: "memory");
    } else {
      asm volatile("s_waitcnt vmcnt(0)" ::: "memory");
    }
    asm volatile("s_barrier" ::: "memory");

    const bf16* Ab = As + buf * (64 * 64);
    const bf16* Bb = Bs + buf * (64 * 64);
    bf16x8 afr[2][2], bfr[2][2];
#pragma unroll
    for (int s = 0; s < 2; ++s) {
      const int cw = s * 4 + quad;
#pragma unroll
      for (int i = 0; i < 2; ++i) {
        const int ra = mW + i * 16 + fragRow;
        afr[s][i] = *(const bf16x8*)&Ab[ra * 64 + ((cw ^ (ra & 7)) << 3)];
        const int rb = nW + i * 16 + fragRow;
        bfr[s][i] = *(const bf16x8*)&Bb[rb * 64 + ((cw ^ (rb & 7)) << 3)];
      }
    }
    asm volatile("s_waitcnt lgkmcnt(0)" ::: "memory");
    asm volatile("s_barrier" ::: "memory");

#pragma unroll
    for (int s = 0; s < 2; ++s)
#pragma unroll
      for (int i = 0; i < 2; ++i)
#pragma unroll
        for (int j = 0; j < 2; ++j)
          acc[i][j] = __builtin_amdgcn_mfma_f32_16x16x32_bf16(afr[s][i], bfr[s][j], acc[i][j], 0, 0, 0);
  }

  const int cCol  = lane & 15;
  const int cRow4 = quad * 4;
#pragma unroll
  for (int i = 0; i < 2; ++i)
#pragma unroll
    for (int j = 0; j < 2; ++j) {
      const int row = m0 + mW + i * 16 + cRow4;
      const int col = n0 + nW + j * 16 + cCol;
#pragma unroll
      for (int r = 0; r < 4; ++r)
        store_out(&C[(size_t)(row + r) * ldc + col], acc[i][j][r]);
    }
}

// ---------------------------------------------------------------------------
// G = x^T x is SYMMETRIC: compute only the 36 upper-triangle 128x128 tiles
// (8 diag + 28 off-diag) instead of all 64 -> 44% less MFMA work and 44%
// less partial-buffer traffic in the biggest kernel. 288 blocks = 36 tiles
// x 8 split-K chunks; z = b&7 -> one K-chunk per XCD, 2 MB xTb slice
// L2-resident, 16x reuse. Partials stored COMPACT: tile t at (z*36+t)*16384,
// ldc=128.
__global__ __launch_bounds__(256) void g_G(
    const bf16* __restrict__ xT, bf16* __restrict__ part)
{
  __shared__ bf16 sm[4 * 128 * 64];  // 64 KB
  const int b = blockIdx.x;
  const int z = b & 7;      // XCD round-robin -> chunk z stays on one XCD
  const int t = b >> 3;     // 36 upper-triangle tiles
  int ti, tj; tri_map(t, ti, tj);
  const bf16* Az = xT + (size_t)z * 1024;
  gemm128_body<bf16>(Az + (size_t)ti * 128 * 8192,
                     Az + (size_t)tj * 128 * 8192,
                     part + ((size_t)(z * 36 + t)) * 16384,
                     0, 0, 1024, 8192, 8192, 128,
                     sm, sm + 2 * 128 * 64);
}

// sum 8 split-K partials per upper tile -> write straight tile AND (for
// off-diagonal) the mirrored lower tile via an XOR-swizzled LDS transpose.
// Swizzle: 8-elem chunk index XORed with row>>3 -> phase-B gather lanes
// (rows seg*8+i, seg distinct per lane) hit distinct banks. 36 blocks.
__global__ __launch_bounds__(256) void reduceT(
    const bf16* __restrict__ part, bf16* __restrict__ G)
{
  __shared__ bf16 red[128 * 128];   // 32 KB
  const int t = blockIdx.x;
  int ti, tj; tri_map(t, ti, tj);
  const int tid = threadIdx.x;
  const size_t base = (size_t)t * 16384;
  const bool diag = (ti == tj);

#pragma unroll
  for (int it = 0; it < 8; ++it) {
    const int flat = it * 256 + tid;          // 8-elem chunk id, 0..2047
    const int row = flat >> 4, chunk = flat & 15;
    float a[8] = {0.f, 0.f, 0.f, 0.f, 0.f, 0.f, 0.f, 0.f};
    for (int z = 0; z < 8; ++z) {
      bf16x8 v = *(const bf16x8*)&part[(size_t)z * 36 * 16384 + base + row * 128 + chunk * 8];
#pragma unroll
      for (int r = 0; r < 8; ++r) a[r] += bf2f(v[r]);
    }
    bf16x8 o;
#pragma unroll
    for (int r = 0; r < 8; ++r) o[r] = bfbits(a[r]);
    *(bf16x8*)&G[(size_t)(ti * 128 + row) * 1024 + tj * 128 + chunk * 8] = o;
    if (!diag)
      *(bf16x8*)&red[row * 128 + ((chunk ^ (row >> 3)) << 3)] = o;
  }
  if (diag) return;                 // diagonal tile is its own mirror
  __syncthreads();

  // transposed write: out-row c of mirror block (tj,ti), 16 lanes x 16B
#pragma unroll
  for (int it = 0; it < 8; ++it) {
    const int flat = it * 256 + tid;
    const int c = flat >> 4, seg = flat & 15;
    const int swz = ((((c >> 3) ^ seg)) << 3) + (c & 7);
    bf16x8 o;
#pragma unroll
    for (int i = 0; i < 8; ++i)
      o[i] = *(const short*)&red[(seg * 8 + i) * 128 + swz];
    *(bf16x8*)&G[(size_t)(tj * 128 + c) * 1024 + ti * 128 + seg * 8] = o;
  }
}

// ---------------------------------------------------------------------------
// dispatch 4: Ut = WV^T G (needs G) || P1 = WQ WK^T (independent, hides in
// the same dispatch -- step 4 alone only fills 1 block/CU). 512 blocks.
__global__ __launch_bounds__(256) void g_ut_p1(
    const bf16* __restrict__ WVT, const bf16* __restrict__ G,
    const bf16* __restrict__ WQb, const bf16* __restrict__ WKb,
    bf16* __restrict__ Ut, bf16* __restrict__ P1)
{
  __shared__ bf16 sm[4 * 64 * 64];
  int b = blockIdx.x;
  if (b < 256) {
    gemm64_body<bf16>(WQb, WKb, P1, b & 15, b >> 4, 1024, 1024, 1024, 1024,
                      sm, sm + 2 * 64 * 64);
  } else {
    b -= 256;
    gemm64_body<bf16>(WVT, G, Ut, b & 15, b >> 4, 1024, 1024, 1024, 1024,
                      sm, sm + 2 * 64 * 64);
  }
}

__global__ __launch_bounds__(256) void gemm64_bf(
    const bf16* __restrict__ A, const bf16* __restrict__ B, bf16* __restrict__ C,
    int K, int lda, int ldb, int ldc)
{
  __shared__ bf16 sm[4 * 64 * 64];
  gemm64_body<bf16>(A, B, C, blockIdx.x, blockIdx.y, K, lda, ldb, ldc,
                    sm, sm + 2 * 64 * 64);
}

// final GEMM: XCD-swizzled so each XCD owns 8 consecutive by (A rows 2 MB,
// L2-resident, 8x reuse). grid 512 = 8 xcd * 8 by * 8 bx.
__global__ __launch_bounds__(256) void gemm128_f32(
    const bf16* __restrict__ A, const bf16* __restrict__ B, float* __restrict__ C,
    int K, int lda, int ldb, int ldc)
{
  __shared__ bf16 sm[4 * 128 * 64];
  const int id = blockIdx.x;
  const int by = ((id & 7) << 3) | ((id >> 3) & 7);
  const int bx = id >> 6;
  gemm128_body<float>(A, B, C, bx, by, K, lda, ldb, ldc, sm, sm + 2 * 128 * 64);
}

// ---------------------------------------------------------------------------
// prep_all, one dispatch (2176 blocks):
//   blocks 0..1023    : transpose x -> xTb AND fused straight-cast x -> xb
//                       (x read ONCE; xTb feeds g_G immediately, so first)
//   blocks 1024..1151 : transpose WV -> WVTb
//   blocks 1152..2175 : flat casts WQ->WQb, WK->WKb (bf16 P1 operands --
//                       the round-1 raw-f32 P1 re-read 128 MB through L3,
//                       reverted)
__global__ __launch_bounds__(256) void prep_all(
    const float* __restrict__ x, const float* __restrict__ WQ,
    const float* __restrict__ WK, const float* __restrict__ WV,
    bf16* __restrict__ xb, bf16* __restrict__ xTb,
    bf16* __restrict__ WQb, bf16* __restrict__ WKb, bf16* __restrict__ WVTb)
{
  __shared__ bf16 t[128][68];   // row stride 68: b64-aligned, low conflict
  int b = blockIdx.x;

  if (b >= 1152) {
    const size_t i = ((size_t)(b - 1152) * 256 + threadIdx.x) * 8;
    const float* src; bf16* dst;
    if (i < 1048576) { src = WQ + i;             dst = WQb + i; }
    else             { src = WK + (i - 1048576); dst = WKb + (i - 1048576); }
    const float4 f0 = *(const float4*)src;
    const float4 f1 = *(const float4*)(src + 4);
    bf16x8 o;
    o[0] = bfbits(f0.x); o[1] = bfbits(f0.y); o[2] = bfbits(f0.z); o[3] = bfbits(f0.w);
    o[4] = bfbits(f1.x); o[5] = bfbits(f1.y); o[6] = bfbits(f1.z); o[7] = bfbits(f1.w);
    *(bf16x8*)dst = o;
    return;
  }

  const float* src; bf16* dst; int ldOut, tr, tc; bool isX;
  if (b < 1024) { src = x;  dst = xTb;  ldOut = SEQ; tr = b >> 4; tc = b & 15; isX = true; }
  else { b -= 1024; src = WV; dst = WVTb; ldOut = DIN; tr = b >> 4; tc = b & 15; isX = false; }
  const int r0 = tr * 128, c0 = tc * 64;

  // phase 1: 128 rows x 64 cols fp32, float4 reads -> short4 LDS writes
  //          (+ fused straight bf16 cast store for x)
#pragma unroll
  for (int p = 0; p < 8; ++p) {
    const int q = threadIdx.x + p * 256;   // float4 id, 0..2047
    const int r = q >> 4, c4 = (q & 15) * 4;
    const float4 f = *(const float4*)&src[(size_t)(r0 + r) * DIN + c0 + c4];
    short4 s4;
    s4.x = bfbits(f.x); s4.y = bfbits(f.y); s4.z = bfbits(f.z); s4.w = bfbits(f.w);
    *(short4*)&t[r][c4] = s4;
    if (isX) *(short4*)&xb[(size_t)(r0 + r) * DIN + c0 + c4] = s4;
  }
  __syncthreads();

  // phase 2: 64 outT-rows x 256 B, bf16x8 16B stores (16 lanes per row)
#pragma unroll
  for (int p = 0; p < 4; ++p) {
    const int h = threadIdx.x + p * 256;   // 0..1023
    const int c = h >> 4, seg = h & 15;
    bf16x8 o;
#pragma unroll
    for (int i = 0; i < 8; ++i)
      o[i] = *(const short*)&t[seg * 8 + i][c];
    *(bf16x8*)&dst[(size_t)(c0 + c) * ldOut + r0 + seg * 8] = o;
  }
}

// ---------------------------------------------------------------------------
extern "C" void kernel_launch(void* const* d_in, const int* in_sizes, int n_in,
                              void* d_out, int out_size, void* d_ws, size_t ws_size,
                              hipStream_t stream)
{
  const float* x  = (const float*)d_in[0];
  const float* WQ = (const float*)d_in[1];
  const float* WK = (const float*)d_in[2];
  const float* WV = (const float*)d_in[3];
  float* out = (float*)d_out;

  char* ws = (char*)d_ws;
  size_t off = 0;
  auto alloc = [&](size_t bytes) -> void* {
    void* p = ws + off;
    off += (bytes + 255) & ~(size_t)255;
    return p;
  };

  const size_t xBytes = (size_t)SEQ * DIN * sizeof(bf16);
  const size_t wBytes = (size_t)DIN * DOUT * sizeof(bf16);

  bf16* xb   = (bf16*)alloc(xBytes);   // x, bf16
  bf16* xTb  = (bf16*)alloc(xBytes);   // x^T, bf16
  bf16* WQb  = (bf16*)alloc(wBytes);
  bf16* WKb  = (bf16*)alloc(wBytes);
  bf16* WVTb = (bf16*)alloc(wBytes);   // WV^T
  bf16* Gb   = (bf16*)alloc(wBytes);   // x^T x (symmetric, full)
  bf16* P1b  = (bf16*)alloc(wBytes);   // WQ WK^T
  bf16* Utb  = (bf16*)alloc(wBytes);   // (G WV)^T = WV^T G
  bf16* WpTb = (bf16*)alloc(wBytes);   // W'^T = Ut P1^T
  bf16* part = (bf16*)alloc((size_t)8 * 36 * 16384 * sizeof(bf16));  // 9.4 MB

  // 1. casts + transposes, one dispatch
  prep_all<<<dim3(2176), 256, 0, stream>>>(x, WQ, WK, WV, xb, xTb, WQb, WKb, WVTb);

  // 2. G upper-triangle split-K partials (XCD-localized), 288 blocks
  g_G<<<dim3(288), 256, 0, stream>>>(xTb, part);

  // 3. G = sum partials, write both triangles (LDS-transposed mirror)
  reduceT<<<dim3(36), 256, 0, stream>>>(part, Gb);

  // 4. Ut = WV^T G  ||  P1 = WQ WK^T  (one 512-block dispatch)
  g_ut_p1<<<dim3(512), 256, 0, stream>>>(WVTb, Gb, WQb, WKb, Utb, P1b);

  // 5. W'^T = Ut P1^T
  gemm64_bf<<<dim3(16, 16), 256, 0, stream>>>(Utb, P1b, WpTb, 1024, 1024, 1024, 1024);

  // 6. out = x W'  (XCD-swizzled)
  gemm128_f32<<<dim3(512), 256, 0, stream>>>(xb, WpTb, out, 1024, 1024, 1024, DOUT);
}

// Round 3
// 157.749 us; speedup vs baseline: 1.0664x; 1.0205x over previous
//
#include <hip/hip_runtime.h>
#include <hip/hip_bf16.h>
#include <stdint.h>
#include <stddef.h>

#define SEQ  8192
#define DIN  1024
#define DOUT 1024

typedef __hip_bfloat16 bf16;
typedef short bf16x8 __attribute__((ext_vector_type(8)));   // 8 bf16 = 4 VGPRs
typedef float f32x4  __attribute__((ext_vector_type(4)));

// async global->LDS, 16B per lane; dest = wave-uniform base + lane*16
#define GLOAD_LDS16(gptr, lptr)                                                     \
  __builtin_amdgcn_global_load_lds(                                                 \
      (const __attribute__((address_space(1))) void*)(gptr),                        \
      (__attribute__((address_space(3))) void*)(lptr), 16, 0, 0)

__device__ inline void store_out(float* p, float v) { *p = v; }
__device__ inline void store_out(bf16* p, float v) { *p = __float2bfloat16(v); }
__device__ inline short bfbits(float f) { bf16 b = __float2bfloat16(f); return *(short*)&b; }
__device__ inline float bf2f(short u) {
  unsigned v = ((unsigned)(unsigned short)u) << 16;
  return __uint_as_float(v);
}

// upper-triangle tile id t in [0,36) -> (ti,tj), ti<=tj, 8x8 tile grid
__device__ inline void tri_map(int t, int& ti, int& tj) {
  int a = 0, rem = t;
  while (rem >= 8 - a) { rem -= 8 - a; ++a; }
  ti = a; tj = a + rem;
}

// ---------------------------------------------------------------------------
// 128x128 tile, BK=64, XOR-swizzled LDS, DOUBLE-BUFFERED (prefetch 1 tile,
// vmcnt(8) one-iter-late wait, raw s_barrier -> no full drain per iter).
// As/Bs each hold 2 buffers of 128*64 bf16 (16 KB) -> 64 KB total LDS.
template <typename OutT>
__device__ __forceinline__ void gemm128_body(
    const bf16* __restrict__ A, const bf16* __restrict__ B, OutT* __restrict__ C,
    int bx, int by, int K, int lda, int ldb, int ldc, bf16* As, bf16* Bs)
{
  const int lane = threadIdx.x & 63;
  const int wave = threadIdx.x >> 6;
  const int m0 = by * 128, n0 = bx * 128;

  const int sR = lane >> 3;
  const int sC = (lane & 7) ^ sR;       // XOR swizzle -> conflict-free b128 reads
  const bf16* gA = A + (size_t)(m0 + sR) * lda + sC * 8;
  const bf16* gB = B + (size_t)(n0 + sR) * ldb + sC * 8;

  f32x4 acc[4][4];
#pragma unroll
  for (int i = 0; i < 4; ++i)
#pragma unroll
    for (int j = 0; j < 4; ++j)
      acc[i][j] = (f32x4){0.f, 0.f, 0.f, 0.f};

  const int wr = wave >> 1, wc = wave & 1;
  const int mW = wr * 64, nW = wc * 64;
  const int fragRow = lane & 15;
  const int quad = lane >> 4;

  auto stage = [&](int kt, int buf) {
    bf16* dA = As + buf * (128 * 64);
    bf16* dB = Bs + buf * (128 * 64);
#pragma unroll
    for (int t = 0; t < 4; ++t) {
      const int R = (t * 4 + wave) * 8;
      GLOAD_LDS16(gA + (size_t)R * lda + kt, &dA[R * 64]);
      GLOAD_LDS16(gB + (size_t)R * ldb + kt, &dB[R * 64]);
    }
  };

  const int nT = K >> 6;
  stage(0, 0);
  for (int kt = 0; kt < nT; ++kt) {
    const int buf = kt & 1;
    if (kt + 1 < nT) {
      stage((kt + 1) << 6, buf ^ 1);
      asm volatile("s_waitcnt vmcnt(8)" ::: "memory");   // wait tile kt only
    } else {
      asm volatile("s_waitcnt vmcnt(0)" ::: "memory");
    }
    asm volatile("s_barrier" ::: "memory");

    const bf16* Ab = As + buf * (128 * 64);
    const bf16* Bb = Bs + buf * (128 * 64);
    bf16x8 afr[2][4], bfr[2][4];
#pragma unroll
    for (int s = 0; s < 2; ++s) {
      const int cw = s * 4 + quad;
#pragma unroll
      for (int i = 0; i < 4; ++i) {
        const int ra = mW + i * 16 + fragRow;
        afr[s][i] = *(const bf16x8*)&Ab[ra * 64 + ((cw ^ (ra & 7)) << 3)];
        const int rb = nW + i * 16 + fragRow;
        bfr[s][i] = *(const bf16x8*)&Bb[rb * 64 + ((cw ^ (rb & 7)) << 3)];
      }
    }
    asm volatile("s_waitcnt lgkmcnt(0)" ::: "memory");   // frags in regs
    asm volatile("s_barrier" ::: "memory");              // buf safe to refill

#pragma unroll
    for (int s = 0; s < 2; ++s)
#pragma unroll
      for (int i = 0; i < 4; ++i)
#pragma unroll
        for (int j = 0; j < 4; ++j)
          acc[i][j] = __builtin_amdgcn_mfma_f32_16x16x32_bf16(afr[s][i], bfr[s][j], acc[i][j], 0, 0, 0);
  }

  const int cCol  = lane & 15;
  const int cRow4 = quad * 4;
#pragma unroll
  for (int i = 0; i < 4; ++i)
#pragma unroll
    for (int j = 0; j < 4; ++j) {
      const int row = m0 + mW + i * 16 + cRow4;
      const int col = n0 + nW + j * 16 + cCol;
#pragma unroll
      for (int r = 0; r < 4; ++r)
        store_out(&C[(size_t)(row + r) * ldc + col], acc[i][j][r]);
    }
}

// 64x64 tile, BK=64, same swizzle, double-buffered. As/Bs each 2*64*64 bf16.
template <typename OutT>
__device__ __forceinline__ void gemm64_body(
    const bf16* __restrict__ A, const bf16* __restrict__ B, OutT* __restrict__ C,
    int bx, int by, int K, int lda, int ldb, int ldc, bf16* As, bf16* Bs)
{
  const int lane = threadIdx.x & 63;
  const int wave = threadIdx.x >> 6;
  const int m0 = by * 64, n0 = bx * 64;

  const int sR = lane >> 3;
  const int sC = (lane & 7) ^ sR;
  const bf16* gA = A + (size_t)(m0 + sR) * lda + sC * 8;
  const bf16* gB = B + (size_t)(n0 + sR) * ldb + sC * 8;

  f32x4 acc[2][2];
#pragma unroll
  for (int i = 0; i < 2; ++i)
#pragma unroll
    for (int j = 0; j < 2; ++j)
      acc[i][j] = (f32x4){0.f, 0.f, 0.f, 0.f};

  const int wr = wave >> 1, wc = wave & 1;
  const int mW = wr * 32, nW = wc * 32;
  const int fragRow = lane & 15;
  const int quad = lane >> 4;

  auto stage = [&](int kt, int buf) {
    bf16* dA = As + buf * (64 * 64);
    bf16* dB = Bs + buf * (64 * 64);
#pragma unroll
    for (int t = 0; t < 2; ++t) {
      const int R = (t * 4 + wave) * 8;
      GLOAD_LDS16(gA + (size_t)R * lda + kt, &dA[R * 64]);
      GLOAD_LDS16(gB + (size_t)R * ldb + kt, &dB[R * 64]);
    }
  };

  const int nT = K >> 6;
  stage(0, 0);
  for (int kt = 0; kt < nT; ++kt) {
    const int buf = kt & 1;
    if (kt + 1 < nT) {
      stage((kt + 1) << 6, buf ^ 1);
      asm volatile("s_waitcnt vmcnt(4)" ::: "memory");
    } else {
      asm volatile("s_waitcnt vmcnt(0)" ::: "memory");
    }
    asm volatile("s_barrier" ::: "memory");

    const bf16* Ab = As + buf * (64 * 64);
    const bf16* Bb = Bs + buf * (64 * 64);
    bf16x8 afr[2][2], bfr[2][2];
#pragma unroll
    for (int s = 0; s < 2; ++s) {
      const int cw = s * 4 + quad;
#pragma unroll
      for (int i = 0; i < 2; ++i) {
        const int ra = mW + i * 16 + fragRow;
        afr[s][i] = *(const bf16x8*)&Ab[ra * 64 + ((cw ^ (ra & 7)) << 3)];
        const int rb = nW + i * 16 + fragRow;
        bfr[s][i] = *(const bf16x8*)&Bb[rb * 64 + ((cw ^ (rb & 7)) << 3)];
      }
    }
    asm volatile("s_waitcnt lgkmcnt(0)" ::: "memory");
    asm volatile("s_barrier" ::: "memory");

#pragma unroll
    for (int s = 0; s < 2; ++s)
#pragma unroll
      for (int i = 0; i < 2; ++i)
#pragma unroll
        for (int j = 0; j < 2; ++j)
          acc[i][j] = __builtin_amdgcn_mfma_f32_16x16x32_bf16(afr[s][i], bfr[s][j], acc[i][j], 0, 0, 0);
  }

  const int cCol  = lane & 15;
  const int cRow4 = quad * 4;
#pragma unroll
  for (int i = 0; i < 2; ++i)
#pragma unroll
    for (int j = 0; j < 2; ++j) {
      const int row = m0 + mW + i * 16 + cRow4;
      const int col = n0 + nW + j * 16 + cCol;
#pragma unroll
      for (int r = 0; r < 4; ++r)
        store_out(&C[(size_t)(row + r) * ldc + col], acc[i][j][r]);
    }
}

// ---------------------------------------------------------------------------
// G = x^T x, upper-triangle tiles only (36 of 64), SPLIT-K 16 (chunks of
// 512 cols): 576 blocks -> critical CU path 3 light blocks (50 MF) vs the
// old 288-block ragged round (2 heavy = 67 MF). XCD locality: z = b&15,
// slices z and z+8 both land on XCD z&7 -> 2 MB combined, L2-resident.
// Partials compact: tile t, chunk z at (z*36+t)*16384, ldc=128.
__global__ __launch_bounds__(256) void g_G(
    const bf16* __restrict__ xT, bf16* __restrict__ part)
{
  __shared__ bf16 sm[4 * 128 * 64];  // 64 KB
  const int b = blockIdx.x;
  const int z = b & 15;     // K-chunk; z&7 -> XCD
  const int t = b >> 4;     // 36 upper-triangle tiles
  int ti, tj; tri_map(t, ti, tj);
  const bf16* Az = xT + (size_t)z * 512;
  gemm128_body<bf16>(Az + (size_t)ti * 128 * 8192,
                     Az + (size_t)tj * 128 * 8192,
                     part + ((size_t)(z * 36 + t)) * 16384,
                     0, 0, 512, 8192, 8192, 128,
                     sm, sm + 2 * 128 * 64);
}

// sum 16 split-K partials -> straight write + (off-diag) LDS-transposed
// mirror write. 288 blocks = 36 tiles x 8 row-slabs of 16 (the old 36-block
// version was latency-bound at 14% CU occupancy on cross-XCD partial reads).
// Phase-B LDS pattern: h splits banks 0-15/16-31; even/odd r share a dword
// (broadcast) -> conflict-free.
__global__ __launch_bounds__(256) void reduceT(
    const bf16* __restrict__ part, bf16* __restrict__ G)
{
  __shared__ bf16 red[16][132];     // 4.2 KB slab
  const int t    = blockIdx.x >> 3;
  const int slab = blockIdx.x & 7;
  int ti, tj; tri_map(t, ti, tj);
  const int tid = threadIdx.x;
  const bool diag = (ti == tj);
  const int rloc  = tid >> 4;              // 0..15 within slab
  const int row   = slab * 16 + rloc;      // tile-local row
  const int chunk = tid & 15;
  const size_t base = (size_t)t * 16384 + row * 128 + chunk * 8;

  float a[8] = {0.f, 0.f, 0.f, 0.f, 0.f, 0.f, 0.f, 0.f};
  for (int z = 0; z < 16; ++z) {
    bf16x8 v = *(const bf16x8*)&part[(size_t)z * 36 * 16384 + base];
#pragma unroll
    for (int r = 0; r < 8; ++r) a[r] += bf2f(v[r]);
  }
  bf16x8 o;
#pragma unroll
  for (int r = 0; r < 8; ++r) o[r] = bfbits(a[r]);
  *(bf16x8*)&G[(size_t)(ti * 128 + row) * 1024 + tj * 128 + chunk * 8] = o;
  if (diag) return;                 // block-uniform: safe before sync
  *(bf16x8*)&red[rloc][chunk * 8] = o;
  __syncthreads();

  // mirror: 128 rows x 16 cols of block (tj,ti); thread -> (row r, half h)
  const int r = tid >> 1, h = tid & 1;
  bf16x8 m;
#pragma unroll
  for (int i = 0; i < 8; ++i)
    m[i] = *(const short*)&red[h * 8 + i][r];
  *(bf16x8*)&G[(size_t)(tj * 128 + r) * 1024 + ti * 128 + slab * 16 + h * 8] = m;
}

// ---------------------------------------------------------------------------
// dispatch 4: Ut = WV^T G (needs G) || P1 = WQ WK^T (independent, hides in
// the same dispatch -- step 4 alone only fills 1 block/CU). 512 blocks.
__global__ __launch_bounds__(256) void g_ut_p1(
    const bf16* __restrict__ WVT, const bf16* __restrict__ G,
    const bf16* __restrict__ WQb, const bf16* __restrict__ WKb,
    bf16* __restrict__ Ut, bf16* __restrict__ P1)
{
  __shared__ bf16 sm[4 * 64 * 64];
  int b = blockIdx.x;
  if (b < 256) {
    gemm64_body<bf16>(WQb, WKb, P1, b & 15, b >> 4, 1024, 1024, 1024, 1024,
                      sm, sm + 2 * 64 * 64);
  } else {
    b -= 256;
    gemm64_body<bf16>(WVT, G, Ut, b & 15, b >> 4, 1024, 1024, 1024, 1024,
                      sm, sm + 2 * 64 * 64);
  }
}

__global__ __launch_bounds__(256) void gemm64_bf(
    const bf16* __restrict__ A, const bf16* __restrict__ B, bf16* __restrict__ C,
    int K, int lda, int ldb, int ldc)
{
  __shared__ bf16 sm[4 * 64 * 64];
  gemm64_body<bf16>(A, B, C, blockIdx.x, blockIdx.y, K, lda, ldb, ldc,
                    sm, sm + 2 * 64 * 64);
}

// final GEMM: XCD-swizzled so each XCD owns 8 consecutive by (A rows 2 MB,
// L2-resident, 8x reuse). grid 512 = 8 xcd * 8 by * 8 bx.
__global__ __launch_bounds__(256) void gemm128_f32(
    const bf16* __restrict__ A, const bf16* __restrict__ B, float* __restrict__ C,
    int K, int lda, int ldb, int ldc)
{
  __shared__ bf16 sm[4 * 128 * 64];
  const int id = blockIdx.x;
  const int by = ((id & 7) << 3) | ((id >> 3) & 7);
  const int bx = id >> 6;
  gemm128_body<float>(A, B, C, bx, by, K, lda, ldb, ldc, sm, sm + 2 * 128 * 64);
}

// ---------------------------------------------------------------------------
// prep_all, one dispatch (2176 blocks):
//   blocks 0..1023    : transpose x -> xTb AND fused straight-cast x -> xb
//                       (x read ONCE; xTb feeds g_G immediately, so first)
//   blocks 1024..1151 : transpose WV -> WVTb
//   blocks 1152..2175 : flat casts WQ->WQb, WK->WKb
__global__ __launch_bounds__(256) void prep_all(
    const float* __restrict__ x, const float* __restrict__ WQ,
    const float* __restrict__ WK, const float* __restrict__ WV,
    bf16* __restrict__ xb, bf16* __restrict__ xTb,
    bf16* __restrict__ WQb, bf16* __restrict__ WKb, bf16* __restrict__ WVTb)
{
  __shared__ bf16 t[128][68];   // row stride 68: b64-aligned, low conflict
  int b = blockIdx.x;

  if (b >= 1152) {
    const size_t i = ((size_t)(b - 1152) * 256 + threadIdx.x) * 8;
    const float* src; bf16* dst;
    if (i < 1048576) { src = WQ + i;             dst = WQb + i; }
    else             { src = WK + (i - 1048576); dst = WKb + (i - 1048576); }
    const float4 f0 = *(const float4*)src;
    const float4 f1 = *(const float4*)(src + 4);
    bf16x8 o;
    o[0] = bfbits(f0.x); o[1] = bfbits(f0.y); o[2] = bfbits(f0.z); o[3] = bfbits(f0.w);
    o[4] = bfbits(f1.x); o[5] = bfbits(f1.y); o[6] = bfbits(f1.z); o[7] = bfbits(f1.w);
    *(bf16x8*)dst = o;
    return;
  }

  const float* src; bf16* dst; int ldOut, tr, tc; bool isX;
  if (b < 1024) { src = x;  dst = xTb;  ldOut = SEQ; tr = b >> 4; tc = b & 15; isX = true; }
  else { b -= 1024; src = WV; dst = WVTb; ldOut = DIN; tr = b >> 4; tc = b & 15; isX = false; }
  const int r0 = tr * 128, c0 = tc * 64;

  // phase 1: 128 rows x 64 cols fp32, float4 reads -> short4 LDS writes
  //          (+ fused straight bf16 cast store for x)
#pragma unroll
  for (int p = 0; p < 8; ++p) {
    const int q = threadIdx.x + p * 256;   // float4 id, 0..2047
    const int r = q >> 4, c4 = (q & 15) * 4;
    const float4 f = *(const float4*)&src[(size_t)(r0 + r) * DIN + c0 + c4];
    short4 s4;
    s4.x = bfbits(f.x); s4.y = bfbits(f.y); s4.z = bfbits(f.z); s4.w = bfbits(f.w);
    *(short4*)&t[r][c4] = s4;
    if (isX) *(short4*)&xb[(size_t)(r0 + r) * DIN + c0 + c4] = s4;
  }
  __syncthreads();

  // phase 2: 64 outT-rows x 256 B, bf16x8 16B stores (16 lanes per row)
#pragma unroll
  for (int p = 0; p < 4; ++p) {
    const int h = threadIdx.x + p * 256;   // 0..1023
    const int c = h >> 4, seg = h & 15;
    bf16x8 o;
#pragma unroll
    for (int i = 0; i < 8; ++i)
      o[i] = *(const short*)&t[seg * 8 + i][c];
    *(bf16x8*)&dst[(size_t)(c0 + c) * ldOut + r0 + seg * 8] = o;
  }
}

// ---------------------------------------------------------------------------
extern "C" void kernel_launch(void* const* d_in, const int* in_sizes, int n_in,
                              void* d_out, int out_size, void* d_ws, size_t ws_size,
                              hipStream_t stream)
{
  const float* x  = (const float*)d_in[0];
  const float* WQ = (const float*)d_in[1];
  const float* WK = (const float*)d_in[2];
  const float* WV = (const float*)d_in[3];
  float* out = (float*)d_out;

  char* ws = (char*)d_ws;
  size_t off = 0;
  auto alloc = [&](size_t bytes) -> void* {
    void* p = ws + off;
    off += (bytes + 255) & ~(size_t)255;
    return p;
  };

  const size_t xBytes = (size_t)SEQ * DIN * sizeof(bf16);
  const size_t wBytes = (size_t)DIN * DOUT * sizeof(bf16);

  bf16* xb   = (bf16*)alloc(xBytes);   // x, bf16
  bf16* xTb  = (bf16*)alloc(xBytes);   // x^T, bf16
  bf16* WQb  = (bf16*)alloc(wBytes);
  bf16* WKb  = (bf16*)alloc(wBytes);
  bf16* WVTb = (bf16*)alloc(wBytes);   // WV^T
  bf16* Gb   = (bf16*)alloc(wBytes);   // x^T x (symmetric, full)
  bf16* P1b  = (bf16*)alloc(wBytes);   // WQ WK^T
  bf16* Utb  = (bf16*)alloc(wBytes);   // (G WV)^T = WV^T G
  bf16* WpTb = (bf16*)alloc(wBytes);   // W'^T = Ut P1^T
  bf16* part = (bf16*)alloc((size_t)16 * 36 * 16384 * sizeof(bf16));  // 18.9 MB

  // 1. casts + transposes, one dispatch
  prep_all<<<dim3(2176), 256, 0, stream>>>(x, WQ, WK, WV, xb, xTb, WQb, WKb, WVTb);

  // 2. G upper-triangle split-K-16 partials (XCD-localized), 576 blocks
  g_G<<<dim3(576), 256, 0, stream>>>(xTb, part);

  // 3. G = sum partials, write both triangles (parallel slabs, 288 blocks)
  reduceT<<<dim3(288), 256, 0, stream>>>(part, Gb);

  // 4. Ut = WV^T G  ||  P1 = WQ WK^T  (one 512-block dispatch)
  g_ut_p1<<<dim3(512), 256, 0, stream>>>(WVTb, Gb, WQb, WKb, Utb, P1b);

  // 5. W'^T = Ut P1^T
  gemm64_bf<<<dim3(16, 16), 256, 0, stream>>>(Utb, P1b, WpTb, 1024, 1024, 1024, 1024);

  // 6. out = x W'  (XCD-swizzled)
  gemm128_f32<<<dim3(512), 256, 0, stream>>>(xb, WpTb, out, 1024, 1024, 1024, DOUT);
}